// Round 3
// baseline (258.372 us; speedup 1.0000x reference)
//
#include <hip/hip_runtime.h>
#include <hip/hip_bf16.h>

// Shapes fixed by the reference: b=1, c=512, t=16, h=w=32
#define CCH   512
#define NPOS  16384
#define NTOK  1024
#define NFRM  16
#define NGRP  32
#define GSZ   (CCH / NGRP)
#define GELEM (GSZ * NPOS)
#define GN_SPLIT 32

typedef unsigned short u16;
typedef unsigned int   u32;
typedef __attribute__((ext_vector_type(8))) short  short8;
typedef __attribute__((ext_vector_type(4))) float  floatx4;

__device__ __forceinline__ float bf2f(u16 u) {
    return __uint_as_float(((u32)u) << 16);
}
__device__ __forceinline__ u16 f2bf(float f) {
    u32 u = __float_as_uint(f);
    u = (u + 0x7fffu + ((u >> 16) & 1u)) >> 16;
    return (u16)u;
}
__device__ __forceinline__ float ldx(const void* p, size_t i, bool f32m) {
    return f32m ? ((const float*)p)[i] : bf2f(((const u16*)p)[i]);
}
// async global->LDS, 16B per lane; LDS base must be wave-uniform
__device__ __forceinline__ void gl2lds16(const u16* g, u16* l) {
    __builtin_amdgcn_global_load_lds(
        (const __attribute__((address_space(1))) u32*)g,
        (__attribute__((address_space(3))) u32*)l, 16, 0, 0);
}

// ------------------------------------------------------------ dtype detect
__launch_bounds__(256)
__global__ void detect_dtype(const u32* __restrict__ x32, u32* __restrict__ flag) {
    __shared__ int cnt;
    if (threadIdx.x == 0) cnt = 0;
    __syncthreads();
    int c = 0;
    for (int i = threadIdx.x; i < 4096; i += 256) {
        u32 v = x32[i] & 0xFFFFu;
        u32 e = (v >> 7) & 0xFFu;
        if (e >= 0xC8u) c++;
    }
    atomicAdd(&cnt, c);
    __syncthreads();
    if (threadIdx.x == 0) *flag = (cnt > 64) ? 1u : 0u;
}

// one-shot conversion of all weights (4x512x512) + biases (4x512) to bf16,
// plus rl zeroing folded in (blocks 1025..1088)
__launch_bounds__(256)
__global__ void conv_all(const void* w0, const void* w1, const void* w2, const void* w3,
                         const void* b0, const void* b1, const void* b2, const void* b3,
                         u16* __restrict__ wdst, u16* __restrict__ bdst,
                         float* __restrict__ rl,
                         const u32* __restrict__ flag) {
    int b = blockIdx.x;
    if (b > 1024) {                       // zero rl: 64 blocks x 256 = 16384 floats
        rl[(b - 1025) * 256 + threadIdx.x] = 0.0f;
        return;
    }
    bool f32m = *flag != 0u;
    if (b < 1024) {                       // weights: 4 x 262144, 1024 elems/block
        int wi = b >> 8;
        const void* src = (wi == 0) ? w0 : (wi == 1) ? w1 : (wi == 2) ? w2 : w3;
        int base = (b & 255) * 1024 + threadIdx.x * 4;
        u16* d = wdst + wi * 262144 + base;
        if (f32m) {
            float4 v = *(const float4*)((const float*)src + base);
            ushort4 o;
            o.x = f2bf(v.x); o.y = f2bf(v.y); o.z = f2bf(v.z); o.w = f2bf(v.w);
            *(ushort4*)d = o;
        } else {
            *(ushort4*)d = *(const ushort4*)((const u16*)src + base);
        }
    } else {                               // biases: 4 x 512, 8 elems/thread
        int t = threadIdx.x;
        int bi = t >> 6;
        int off = (t & 63) * 8;
        const void* src = (bi == 0) ? b0 : (bi == 1) ? b1 : (bi == 2) ? b2 : b3;
        u16* d = bdst + bi * 512 + off;
        if (f32m) {
            float4 v1 = *(const float4*)((const float*)src + off);
            float4 v2 = *(const float4*)((const float*)src + off + 4);
            ushort4 o1, o2;
            o1.x = f2bf(v1.x); o1.y = f2bf(v1.y); o1.z = f2bf(v1.z); o1.w = f2bf(v1.w);
            o2.x = f2bf(v2.x); o2.y = f2bf(v2.y); o2.z = f2bf(v2.z); o2.w = f2bf(v2.w);
            *(ushort4*)d = o1; *(ushort4*)(d + 4) = o2;
        } else {
            *(ushort4*)d = *(const ushort4*)((const u16*)src + off);
            *(ushort4*)(d + 4) = *(const ushort4*)((const u16*)src + off + 4);
        }
    }
}

// ------------------------------------------------- GroupNorm stage 1: partials
__launch_bounds__(256)
__global__ void gn_partial(const void* __restrict__ x, float2* __restrict__ partials,
                           const u32* __restrict__ flag) {
    __shared__ float sm[8];
    bool f32m = *flag != 0u;
    const int chunk = GELEM / GN_SPLIT;           // 8192 elements
    size_t base = (size_t)blockIdx.x * chunk;
    float s = 0.f, ss = 0.f;
    if (f32m) {
        const float4* p = (const float4*)((const float*)x + base);
        for (int i = threadIdx.x; i < chunk / 4; i += 256) {
            float4 u = p[i];
            s  += u.x + u.y + u.z + u.w;
            ss += u.x * u.x + u.y * u.y + u.z * u.z + u.w * u.w;
        }
    } else {
        const ushort4* p = (const ushort4*)((const u16*)x + base);
        for (int i = threadIdx.x; i < chunk / 4; i += 256) {
            ushort4 u = p[i];
            float a = bf2f(u.x), b = bf2f(u.y), c = bf2f(u.z), d = bf2f(u.w);
            s  += a + b + c + d;
            ss += a * a + b * b + c * c + d * d;
        }
    }
    int lane = threadIdx.x & 63, w = threadIdx.x >> 6;
    float t = s;
    #pragma unroll
    for (int o = 32; o > 0; o >>= 1) t += __shfl_down(t, o, 64);
    if (lane == 0) sm[w] = t;
    t = ss;
    #pragma unroll
    for (int o = 32; o > 0; o >>= 1) t += __shfl_down(t, o, 64);
    if (lane == 0) sm[4 + w] = t;
    __syncthreads();
    if (threadIdx.x == 0)
        partials[blockIdx.x] = make_float2(sm[0] + sm[1] + sm[2] + sm[3],
                                           sm[4] + sm[5] + sm[6] + sm[7]);
}

// stage 2: fold partials per group, emit per-channel affine (xn = x*sc + sh)
__launch_bounds__(256)
__global__ void gn_coef(const float2* __restrict__ partials, const void* __restrict__ gamma,
                        const void* __restrict__ beta, float2* __restrict__ coef,
                        const u32* __restrict__ flag) {
    bool f32m = *flag != 0u;
    int c = blockIdx.x * 256 + threadIdx.x;
    if (c < CCH) {
        int g = c >> 4;
        float sum = 0.f, sq = 0.f;
        #pragma unroll
        for (int i = 0; i < GN_SPLIT; ++i) {
            float2 p = partials[g * GN_SPLIT + i];
            sum += p.x; sq += p.y;
        }
        float mean = sum * (1.0f / (float)GELEM);
        float var  = fmaxf(sq * (1.0f / (float)GELEM) - mean * mean, 0.0f);
        float rstd = rsqrtf(var + 1e-6f);
        float gm = ldx(gamma, c, f32m), b = ldx(beta, c, f32m);
        float sc = rstd * gm;
        coef[c] = make_float2(sc, b - mean * sc);
    }
}

// GN-apply + transpose: x [c][pos] (poly) -> xn_t [pos][c] (bf16)
__launch_bounds__(256)
__global__ void gn_apply_t(const void* __restrict__ x, const float2* __restrict__ coef,
                           u16* __restrict__ xt, const u32* __restrict__ flag) {
    bool f32m = *flag != 0u;
    __shared__ float tile[64][65];
    int p0 = blockIdx.x * 64, c0 = blockIdx.y * 64;
    int lane = threadIdx.x & 63, rg = threadIdx.x >> 6;
    #pragma unroll 4
    for (int i = 0; i < 16; ++i) {
        int row = rg * 16 + i;
        int c = c0 + row;
        float2 cf = coef[c];
        float v = ldx(x, (size_t)c * NPOS + p0 + lane, f32m);
        tile[row][lane] = v * cf.x + cf.y;
    }
    __syncthreads();
    #pragma unroll 4
    for (int i = 0; i < 16; ++i) {
        int prow = rg * 16 + i;
        xt[(size_t)(p0 + prow) * CCH + c0 + lane] = f2bf(tile[lane][prow]);
    }
}

// --------------------------------------------------------- MFMA TN GEMM
// C[m][n] = sum_k A[m*lda+k] * B[n*ldb+k], 128x128 tile, BK=32,
// 3-BUFFER 2-DEEP PIPELINE with counted vmcnt (T4, §5.5):
//   prologue stages tiles 0,1; each iter: s_waitcnt vmcnt(4) (tile i done,
//   tile i+1 STAYS IN FLIGHT across the raw s_barrier), then stage tile i+2.
//   Hiding window per stage ~= 2 full K-steps (was <1 compute phase with
//   __syncthreads's vmcnt(0) drain). In-order vmcnt retirement guarantees
//   oldest-stage-done; per-wave wait + barrier => whole tile resident for
//   all waves. Buffer (i+2)%3 is tile (i-1)'s buffer, whose ds_reads were
//   consumed by iter i-1's MFMAs before this wave reached barrier(i).
// LDS swizzle (rule #21, both-sides): LDS[r][p] = G[r][p ^ ((r>>1)&3)];
//   linear LDS dest (global_load_lds reqmt), pre-swizzled global source,
//   same XOR on ds_read -> 2-way max bank aliasing = free (m136).
// MX:  m-block on blockIdx.x (XCD-local A-tile reuse for tall C).
// FSW: frame->XCD pinning swizzle for z-batched GEMMs.
#define EPI_QK    0   // C bf16, += bias[n]
#define EPI_V     1   // C bf16, += bias[m]
#define EPI_SCEXP 2   // C bf16 = exp(v*scale); rowsum atomically into rl
#define EPI_PV    3   // C bf16 = v / rl[f*NTOK+m]
#define EPI_OUT   4   // C poly, += bias[m] + resid[idx]

template<int EPI, bool MX, bool FSW>
__launch_bounds__(256, 3)   // 3 blocks/CU (LDS 48KB); VGPR cap 168
__global__ void mfma_gemm(const u16* __restrict__ A, const u16* __restrict__ B,
                          void* __restrict__ C, const u16* __restrict__ bias,
                          const void* __restrict__ resid, const u32* __restrict__ flag,
                          float* __restrict__ rl,
                          int lda, int ldb, int ldc, int K,
                          long aFS, long bFS, long cFS) {
    __shared__ __align__(16) u16 As[3][128 * 32];   // 3 x 8 KB
    __shared__ __align__(16) u16 Bs[3][128 * 32];
    const int tid = threadIdx.x;

    int bxi, byi, f;
    if (FSW) {
        u32 id = (blockIdx.z * gridDim.y + blockIdx.y) * gridDim.x + blockIdx.x;
        u32 T = gridDim.x * gridDim.y * gridDim.z;
        u32 half = T >> 1;
        f = (int)(id & 7u) + ((id >= half) ? 8 : 0);
        u32 l = (id >= half ? id - half : id) >> 3;
        bxi = (int)(l % gridDim.x);
        byi = (int)(l / gridDim.x);
    } else {
        bxi = blockIdx.x; byi = blockIdx.y; f = blockIdx.z;
    }
    const int m_blk = MX ? bxi : byi;
    const int n_blk = MX ? byi : bxi;

    const u16* Ab = A + (size_t)f * aFS + (size_t)m_blk * 128 * lda;
    const u16* Bb = B + (size_t)f * bFS + (size_t)n_blk * 128 * ldb;

    const int wave = tid >> 6, lane = tid & 63;
    // staging: per call 16 rows x 4 chunks of 16B; source chunk pre-swizzled
    // so LDS[r][p] = G[r][p ^ ((r>>1)&3)]
    const int srow = wave * 32 + (lane >> 2);
    const int scol = ((lane & 3) ^ ((lane >> 3) & 3)) * 8;   // u16 units

    const int wm = (wave >> 1) * 64, wn = (wave & 1) * 64;
    const int l15 = lane & 15, quad = lane >> 4;
    const int rsw = (l15 >> 1) & 3;                          // read-side XOR field

    floatx4 acc[4][4] = {};
    const int nt = K >> 5;                                   // K-steps (BK=32)

    auto stage = [&](int b, int kk) {
        #pragma unroll
        for (int o = 0; o < 2; ++o) {
            gl2lds16(Ab + (size_t)(srow + o * 16) * lda + kk + scol,
                     &As[b][wave * 1024 + o * 512]);
            gl2lds16(Bb + (size_t)(srow + o * 16) * ldb + kk + scol,
                     &Bs[b][wave * 1024 + o * 512]);
        }
    };

    stage(0, 0);                    // 4 VMEM ops/wave per stage
    if (nt > 1) stage(1, 32);
    int nxt = 2;
    for (int i = 0; i < nt; ++i) {
        if (i + 1 < nt) {
            asm volatile("s_waitcnt vmcnt(4)" ::: "memory");  // tile i done; i+1 flying
        } else {
            asm volatile("s_waitcnt vmcnt(0)" ::: "memory");  // last tile: drain
        }
        __builtin_amdgcn_sched_barrier(0);
        __builtin_amdgcn_s_barrier();        // raw: no vmcnt(0) drain of tile i+1
        if (nxt < nt) { stage(nxt % 3, nxt << 5); ++nxt; }
        const int cur = i % 3;
        short8 af[4], bf[4];
        #pragma unroll
        for (int mi = 0; mi < 4; ++mi)
            af[mi] = *(const short8*)&As[cur][(wm + mi * 16 + l15) * 32 + ((quad ^ rsw) << 3)];
        #pragma unroll
        for (int ni = 0; ni < 4; ++ni)
            bf[ni] = *(const short8*)&Bs[cur][(wn + ni * 16 + l15) * 32 + ((quad ^ rsw) << 3)];
        #pragma unroll
        for (int mi = 0; mi < 4; ++mi)
            #pragma unroll
            for (int ni = 0; ni < 4; ++ni)
                acc[mi][ni] = __builtin_amdgcn_mfma_f32_16x16x32_bf16(
                    af[mi], bf[ni], acc[mi][ni], 0, 0, 0);
    }

    const bool f32m = (EPI == EPI_OUT) ? (*flag != 0u) : false;
    const int m_base = m_blk * 128 + wm;
    const int n_base = n_blk * 128 + wn;
    const float scale = 0.044194173824159216f;  // 512^-0.5

    float inv[4][4];
    if (EPI == EPI_PV) {
        #pragma unroll
        for (int mi = 0; mi < 4; ++mi)
            #pragma unroll
            for (int r = 0; r < 4; ++r)
                inv[mi][r] = 1.0f / rl[f * NTOK + m_base + mi * 16 + quad * 4 + r];
    }
    float rs[4][4];
    if (EPI == EPI_SCEXP) {
        #pragma unroll
        for (int mi = 0; mi < 4; ++mi)
            #pragma unroll
            for (int r = 0; r < 4; ++r) rs[mi][r] = 0.0f;
    }

    #pragma unroll
    for (int mi = 0; mi < 4; ++mi) {
        #pragma unroll
        for (int ni = 0; ni < 4; ++ni) {
            int n = n_base + ni * 16 + l15;
            float bn = (EPI == EPI_QK) ? bf2f(bias[n]) : 0.0f;
            #pragma unroll
            for (int r = 0; r < 4; ++r) {
                int m = m_base + mi * 16 + quad * 4 + r;
                float v = acc[mi][ni][r];
                size_t idx = (size_t)f * cFS + (size_t)m * ldc + n;
                if (EPI == EPI_QK) {
                    ((u16*)C)[idx] = f2bf(v + bn);
                } else if (EPI == EPI_V) {
                    ((u16*)C)[idx] = f2bf(v + bf2f(bias[m]));
                } else if (EPI == EPI_SCEXP) {
                    float ex = __expf(v * scale);
                    rs[mi][r] += ex;
                    ((u16*)C)[idx] = f2bf(ex);
                } else if (EPI == EPI_PV) {
                    ((u16*)C)[idx] = f2bf(v * inv[mi][r]);
                } else {  // EPI_OUT
                    float r2 = v + bf2f(bias[m]) + ldx(resid, idx, f32m);
                    if (f32m) ((float*)C)[idx] = r2;
                    else      ((u16*)C)[idx]   = f2bf(r2);
                }
            }
        }
    }

    if (EPI == EPI_SCEXP) {
        #pragma unroll
        for (int mi = 0; mi < 4; ++mi) {
            #pragma unroll
            for (int r = 0; r < 4; ++r) {
                float s = rs[mi][r];
                s += __shfl_xor(s, 1, 64);
                s += __shfl_xor(s, 2, 64);
                s += __shfl_xor(s, 4, 64);
                s += __shfl_xor(s, 8, 64);
                if (l15 == 0)
                    atomicAdd(&rl[f * NTOK + m_base + mi * 16 + quad * 4 + r], s);
            }
        }
    }
}

// ---------------------------------------------------------------- launcher
extern "C" void kernel_launch(void* const* d_in, const int* in_sizes, int n_in,
                              void* d_out, int out_size, void* d_ws, size_t ws_size,
                              hipStream_t stream) {
    const void* x   = d_in[0];
    const void* gam = d_in[1];
    const void* bet = d_in[2];

    // Workspace (100 MiB):
    //   [0,4K) coef  [4K,+8K) partials  [12352) flag
    //   [16K,+2Mi) bf16 weights (contig)  [~2.1Mi,+4K) bf16 biases (contig)
    //   [3Mi) rl (16384 f32)
    //   [4Mi) xnt 16Mi (reused as obuf)  [20Mi) qkt 32Mi (q cols 0..511, k cols 512..1023)
    //   [52Mi) vt 16Mi
    //   [68Mi) P bf16 16x1024x1024 = 32Mi
    char* ws = (char*)d_ws;
    float2* coef     = (float2*)(ws);
    float2* partials = (float2*)(ws + 4096);
    u32*    flag     = (u32*)(ws + 12352);
    u16* cw[4] = { (u16*)(ws + 16384),              (u16*)(ws + 16384 +  524288ull),
                   (u16*)(ws + 16384 + 1048576ull), (u16*)(ws + 16384 + 1572864ull) };
    u16* cb[4] = { (u16*)(ws + 2113536ull),        (u16*)(ws + 2113536ull + 1024),
                   (u16*)(ws + 2113536ull + 2048), (u16*)(ws + 2113536ull + 3072) };
    float* rl  = (float*)(ws + (3ull << 20));
    u16*  xnt  = (u16*)(ws + (4ull  << 20));
    u16*  qkt  = (u16*)(ws + (20ull << 20));
    u16*  vt   = (u16*)(ws + (52ull << 20));
    u16*  pbuf = (u16*)(ws + (68ull << 20));
    u16*  obuf = xnt;

    detect_dtype<<<1, 256, 0, stream>>>((const u32*)x, flag);
    // conv_all also zeroes rl (blocks 1025..1088)
    conv_all<<<1089, 256, 0, stream>>>(d_in[3], d_in[5], d_in[7], d_in[9],
                                       d_in[4], d_in[6], d_in[8], d_in[10],
                                       cw[0], cb[0], rl, flag);
    gn_partial<<<NGRP * GN_SPLIT, 256, 0, stream>>>(x, partials, flag);
    gn_coef<<<2, 256, 0, stream>>>(partials, gam, bet, coef, flag);
    gn_apply_t<<<dim3(NPOS / 64, CCH / 64), 256, 0, stream>>>(x, coef, xnt, flag);

    // q,k fused: cw[0],cw[1] contiguous -> one GEMM, C[pos][1024] (q|k), one
    // xnt pass instead of two. m on x so n-blocks sharing an xnt tile are XCD-local.
    dim3 gqk(NPOS / 128, 1024 / 128, 1);   // (128, 8)
    mfma_gemm<EPI_QK, true, false><<<gqk, 256, 0, stream>>>(
        xnt, cw[0], qkt, cb[0], nullptr, flag, nullptr, CCH, CCH, 1024, CCH, 0, 0, 0);
    // v: C[cout][pos], A=Wv, B=xnt (B-tile sharing already XCD-local: x-dim=n=128)
    dim3 gv(NPOS / 128, CCH / 128, 1);    // (128, 4)
    mfma_gemm<EPI_V, false, false><<<gv, 256, 0, stream>>>(
        cw[2], xnt, vt, cb[2], nullptr, flag, nullptr, CCH, CCH, NPOS, CCH, 0, 0, 0);

    // scores + exp + rowsum: P[f][i][j] = exp(scale * q_i.k_j), rl[f*1024+i] = sum_j
    // A = q rows of qkt, B = k rows (qkt+512), both lda/ldb = 1024
    dim3 gsc(NTOK / 128, NTOK / 128, NFRM);   // (8, 8, 16), frame->XCD pinned
    mfma_gemm<EPI_SCEXP, false, true><<<gsc, 256, 0, stream>>>(
        qkt, qkt + 512, pbuf, nullptr, nullptr, flag, rl, 1024, 1024, NTOK, CCH,
        (long)NTOK * 1024, (long)NTOK * 1024, (long)NTOK * NTOK);

    // PV: obuf[i][c] = (P_i . V_c) / rl[i]
    dim3 gpv(CCH / 128, NTOK / 128, NFRM);    // (4, 8, 16), frame->XCD pinned
    mfma_gemm<EPI_PV, false, true><<<gpv, 256, 0, stream>>>(
        pbuf, vt, obuf, nullptr, nullptr, flag, rl, NTOK, NPOS, CCH, NTOK,
        (long)NTOK * NTOK, NTOK, (long)NTOK * CCH);

    // out: C[cout][pos] = Wo . O + bo + x, poly store
    dim3 go(NPOS / 128, CCH / 128, 1);    // (128, 4)
    mfma_gemm<EPI_OUT, false, false><<<go, 256, 0, stream>>>(
        cw[3], obuf, d_out, cb[3], x, flag, nullptr, CCH, CCH, NPOS, CCH, 0, 0, 0);
}

// Round 4
// 236.340 us; speedup vs baseline: 1.0932x; 1.0932x over previous
//
#include <hip/hip_runtime.h>
#include <hip/hip_bf16.h>

// Shapes fixed by the reference: b=1, c=512, t=16, h=w=32
#define CCH   512
#define NPOS  16384
#define NTOK  1024
#define NFRM  16
#define NGRP  32
#define GSZ   (CCH / NGRP)
#define GELEM (GSZ * NPOS)
#define GN_SPLIT 32

typedef unsigned short u16;
typedef unsigned int   u32;
typedef __attribute__((ext_vector_type(8))) short  short8;
typedef __attribute__((ext_vector_type(4))) float  floatx4;

__device__ __forceinline__ float bf2f(u16 u) {
    return __uint_as_float(((u32)u) << 16);
}
__device__ __forceinline__ u16 f2bf(float f) {
    u32 u = __float_as_uint(f);
    u = (u + 0x7fffu + ((u >> 16) & 1u)) >> 16;
    return (u16)u;
}
__device__ __forceinline__ float ldx(const void* p, size_t i, bool f32m) {
    return f32m ? ((const float*)p)[i] : bf2f(((const u16*)p)[i]);
}
// async global->LDS, 16B per lane; LDS base must be wave-uniform
__device__ __forceinline__ void gl2lds16(const u16* g, u16* l) {
    __builtin_amdgcn_global_load_lds(
        (const __attribute__((address_space(1))) u32*)g,
        (__attribute__((address_space(3))) u32*)l, 16, 0, 0);
}

// ------------------------------------------------------------ dtype detect
__launch_bounds__(256)
__global__ void detect_dtype(const u32* __restrict__ x32, u32* __restrict__ flag) {
    __shared__ int cnt;
    if (threadIdx.x == 0) cnt = 0;
    __syncthreads();
    int c = 0;
    for (int i = threadIdx.x; i < 4096; i += 256) {
        u32 v = x32[i] & 0xFFFFu;
        u32 e = (v >> 7) & 0xFFu;
        if (e >= 0xC8u) c++;
    }
    atomicAdd(&cnt, c);
    __syncthreads();
    if (threadIdx.x == 0) *flag = (cnt > 64) ? 1u : 0u;
}

// one-shot conversion of all weights (4x512x512) + biases (4x512) to bf16,
// plus rl zeroing folded in (blocks 1025..1088)
__launch_bounds__(256)
__global__ void conv_all(const void* w0, const void* w1, const void* w2, const void* w3,
                         const void* b0, const void* b1, const void* b2, const void* b3,
                         u16* __restrict__ wdst, u16* __restrict__ bdst,
                         float* __restrict__ rl,
                         const u32* __restrict__ flag) {
    int b = blockIdx.x;
    if (b > 1024) {                       // zero rl: 64 blocks x 256 = 16384 floats
        rl[(b - 1025) * 256 + threadIdx.x] = 0.0f;
        return;
    }
    bool f32m = *flag != 0u;
    if (b < 1024) {                       // weights: 4 x 262144, 1024 elems/block
        int wi = b >> 8;
        const void* src = (wi == 0) ? w0 : (wi == 1) ? w1 : (wi == 2) ? w2 : w3;
        int base = (b & 255) * 1024 + threadIdx.x * 4;
        u16* d = wdst + wi * 262144 + base;
        if (f32m) {
            float4 v = *(const float4*)((const float*)src + base);
            ushort4 o;
            o.x = f2bf(v.x); o.y = f2bf(v.y); o.z = f2bf(v.z); o.w = f2bf(v.w);
            *(ushort4*)d = o;
        } else {
            *(ushort4*)d = *(const ushort4*)((const u16*)src + base);
        }
    } else {                               // biases: 4 x 512, 8 elems/thread
        int t = threadIdx.x;
        int bi = t >> 6;
        int off = (t & 63) * 8;
        const void* src = (bi == 0) ? b0 : (bi == 1) ? b1 : (bi == 2) ? b2 : b3;
        u16* d = bdst + bi * 512 + off;
        if (f32m) {
            float4 v1 = *(const float4*)((const float*)src + off);
            float4 v2 = *(const float4*)((const float*)src + off + 4);
            ushort4 o1, o2;
            o1.x = f2bf(v1.x); o1.y = f2bf(v1.y); o1.z = f2bf(v1.z); o1.w = f2bf(v1.w);
            o2.x = f2bf(v2.x); o2.y = f2bf(v2.y); o2.z = f2bf(v2.z); o2.w = f2bf(v2.w);
            *(ushort4*)d = o1; *(ushort4*)(d + 4) = o2;
        } else {
            *(ushort4*)d = *(const ushort4*)((const u16*)src + off);
            *(ushort4*)(d + 4) = *(const ushort4*)((const u16*)src + off + 4);
        }
    }
}

// ------------------------------------------------- GroupNorm stage 1: partials
__launch_bounds__(256)
__global__ void gn_partial(const void* __restrict__ x, float2* __restrict__ partials,
                           const u32* __restrict__ flag) {
    __shared__ float sm[8];
    bool f32m = *flag != 0u;
    const int chunk = GELEM / GN_SPLIT;           // 8192 elements
    size_t base = (size_t)blockIdx.x * chunk;
    float s = 0.f, ss = 0.f;
    if (f32m) {
        const float4* p = (const float4*)((const float*)x + base);
        for (int i = threadIdx.x; i < chunk / 4; i += 256) {
            float4 u = p[i];
            s  += u.x + u.y + u.z + u.w;
            ss += u.x * u.x + u.y * u.y + u.z * u.z + u.w * u.w;
        }
    } else {
        const ushort4* p = (const ushort4*)((const u16*)x + base);
        for (int i = threadIdx.x; i < chunk / 4; i += 256) {
            ushort4 u = p[i];
            float a = bf2f(u.x), b = bf2f(u.y), c = bf2f(u.z), d = bf2f(u.w);
            s  += a + b + c + d;
            ss += a * a + b * b + c * c + d * d;
        }
    }
    int lane = threadIdx.x & 63, w = threadIdx.x >> 6;
    float t = s;
    #pragma unroll
    for (int o = 32; o > 0; o >>= 1) t += __shfl_down(t, o, 64);
    if (lane == 0) sm[w] = t;
    t = ss;
    #pragma unroll
    for (int o = 32; o > 0; o >>= 1) t += __shfl_down(t, o, 64);
    if (lane == 0) sm[4 + w] = t;
    __syncthreads();
    if (threadIdx.x == 0)
        partials[blockIdx.x] = make_float2(sm[0] + sm[1] + sm[2] + sm[3],
                                           sm[4] + sm[5] + sm[6] + sm[7]);
}

// stage 2: fold partials per group, emit per-channel affine (xn = x*sc + sh)
__launch_bounds__(256)
__global__ void gn_coef(const float2* __restrict__ partials, const void* __restrict__ gamma,
                        const void* __restrict__ beta, float2* __restrict__ coef,
                        const u32* __restrict__ flag) {
    bool f32m = *flag != 0u;
    int c = blockIdx.x * 256 + threadIdx.x;
    if (c < CCH) {
        int g = c >> 4;
        float sum = 0.f, sq = 0.f;
        #pragma unroll
        for (int i = 0; i < GN_SPLIT; ++i) {
            float2 p = partials[g * GN_SPLIT + i];
            sum += p.x; sq += p.y;
        }
        float mean = sum * (1.0f / (float)GELEM);
        float var  = fmaxf(sq * (1.0f / (float)GELEM) - mean * mean, 0.0f);
        float rstd = rsqrtf(var + 1e-6f);
        float gm = ldx(gamma, c, f32m), b = ldx(beta, c, f32m);
        float sc = rstd * gm;
        coef[c] = make_float2(sc, b - mean * sc);
    }
}

// GN-apply + transpose: x [c][pos] (poly) -> xn_t [pos][c] (bf16)
__launch_bounds__(256)
__global__ void gn_apply_t(const void* __restrict__ x, const float2* __restrict__ coef,
                           u16* __restrict__ xt, const u32* __restrict__ flag) {
    bool f32m = *flag != 0u;
    __shared__ float tile[64][65];
    int p0 = blockIdx.x * 64, c0 = blockIdx.y * 64;
    int lane = threadIdx.x & 63, rg = threadIdx.x >> 6;
    #pragma unroll 4
    for (int i = 0; i < 16; ++i) {
        int row = rg * 16 + i;
        int c = c0 + row;
        float2 cf = coef[c];
        float v = ldx(x, (size_t)c * NPOS + p0 + lane, f32m);
        tile[row][lane] = v * cf.x + cf.y;
    }
    __syncthreads();
    #pragma unroll 4
    for (int i = 0; i < 16; ++i) {
        int prow = rg * 16 + i;
        xt[(size_t)(p0 + prow) * CCH + c0 + lane] = f2bf(tile[lane][prow]);
    }
}

// --------------------------------------------------------- MFMA TN GEMM
// C[m][n] = sum_k A[m*lda+k] * B[n*ldb+k], BMx128 tile, BK=64.
// ROUND-1 CORE (best measured; rounds 2-3's in-block pipelining regressed,
// m131-m140 repeat): single LDS buffer, two __syncthreads per K-step; stage
// latency is hidden by OTHER resident blocks (2+ blocks/CU required).
// BM=256 variant (512 thr, 8 waves 4m x 2n): +33% MFMA/staged-byte
// (48KB -> 256 wave-MFMAs vs 32KB -> 128), half the blocks (half the
// prologue/epilogue instances), 6 vs 8 staging ops/thread/step. Still
// 2 blocks/CU (LDS 48KB, VGPR capped 128 via __launch_bounds__(512,4)).
// Used only where grid stays >= 2 blocks/CU (QK-fused, SCEXP).
// LDS swizzle (rule #21, both-sides): LDS[r][p] = G[r][p ^ (r&7)], p=16B
// chunk 0..7; linear LDS dest (global_load_lds reqmt), pre-swizzled global
// source, same XOR on ds_read -> conflict-free (measured 0 in round 1).
// MX:  m-block on blockIdx.x (XCD-local A-tile reuse for tall C).
// FSW: frame->XCD pinning swizzle for z-batched GEMMs.
#define EPI_QK    0   // C bf16, += bias[n]
#define EPI_V     1   // C bf16, += bias[m]
#define EPI_SCEXP 2   // C bf16 = exp(v*scale); rowsum atomically into rl
#define EPI_PV    3   // C bf16 = v / rl[f*NTOK+m]
#define EPI_OUT   4   // C poly, += bias[m] + resid[idx]

template<int EPI, bool MX, bool FSW, int BM>
__launch_bounds__(BM == 256 ? 512 : 256, BM == 256 ? 4 : 3)
__global__ void mfma_gemm(const u16* __restrict__ A, const u16* __restrict__ B,
                          void* __restrict__ C, const u16* __restrict__ bias,
                          const void* __restrict__ resid, const u32* __restrict__ flag,
                          float* __restrict__ rl,
                          int lda, int ldb, int ldc, int K,
                          long aFS, long bFS, long cFS) {
    __shared__ __align__(16) u16 As[BM * 64];    // 16 or 32 KB, linear
    __shared__ __align__(16) u16 Bs[128 * 64];   // 16 KB
    const int tid = threadIdx.x;

    int bxi, byi, f;
    if (FSW) {
        u32 id = (blockIdx.z * gridDim.y + blockIdx.y) * gridDim.x + blockIdx.x;
        u32 T = gridDim.x * gridDim.y * gridDim.z;
        u32 half = T >> 1;
        f = (int)(id & 7u) + ((id >= half) ? 8 : 0);
        u32 l = (id >= half ? id - half : id) >> 3;
        bxi = (int)(l % gridDim.x);
        byi = (int)(l / gridDim.x);
    } else {
        bxi = blockIdx.x; byi = blockIdx.y; f = blockIdx.z;
    }
    const int m_blk = MX ? bxi : byi;
    const int n_blk = MX ? byi : bxi;

    const u16* Ab = A + (size_t)f * aFS + (size_t)m_blk * BM * lda;
    const u16* Bb = B + (size_t)f * bFS + (size_t)n_blk * 128 * ldb;

    const int wave = tid >> 6, lane = tid & 63;
    // staging: per call, 8 rows x 8 chunks of 16B; global col chunk is
    // pre-swizzled so that LDS[r][p] = G[r][p ^ (r&7)]
    const int srowA = wave * 32 + (lane >> 3);                       // 4 calls: 32 rows/wave
    const int srowB = (BM == 256) ? (wave * 16 + (lane >> 3)) : srowA; // 2 or 4 calls
    const int schs  = ((lane & 7) ^ ((lane >> 3) & 7)) * 8;

    const int wm = (wave >> 1) * 64, wn = (wave & 1) * 64;   // 4mx2n (BM=256) / 2mx2n
    const int l15 = lane & 15, quad = lane >> 4;

    floatx4 acc[4][4] = {};

    for (int kk = 0; kk < K; kk += 64) {
        __syncthreads();
        #pragma unroll
        for (int o = 0; o < 4; ++o)
            gl2lds16(Ab + (size_t)(srowA + o * 8) * lda + kk + schs,
                     &As[wave * 2048 + o * 512]);
        if constexpr (BM == 256) {
            #pragma unroll
            for (int o = 0; o < 2; ++o)
                gl2lds16(Bb + (size_t)(srowB + o * 8) * ldb + kk + schs,
                         &Bs[wave * 1024 + o * 512]);
        } else {
            #pragma unroll
            for (int o = 0; o < 4; ++o)
                gl2lds16(Bb + (size_t)(srowB + o * 8) * ldb + kk + schs,
                         &Bs[wave * 2048 + o * 512]);
        }
        __syncthreads();
        #pragma unroll
        for (int kh = 0; kh < 2; ++kh) {
            short8 af[4], bf[4];
            #pragma unroll
            for (int mi = 0; mi < 4; ++mi) {
                const int row = wm + mi * 16 + l15;
                af[mi] = *(const short8*)&As[row * 64 + (((kh << 2) | quad) ^ (row & 7)) * 8];
            }
            #pragma unroll
            for (int ni = 0; ni < 4; ++ni) {
                const int row = wn + ni * 16 + l15;
                bf[ni] = *(const short8*)&Bs[row * 64 + (((kh << 2) | quad) ^ (row & 7)) * 8];
            }
            #pragma unroll
            for (int mi = 0; mi < 4; ++mi)
                #pragma unroll
                for (int ni = 0; ni < 4; ++ni)
                    acc[mi][ni] = __builtin_amdgcn_mfma_f32_16x16x32_bf16(
                        af[mi], bf[ni], acc[mi][ni], 0, 0, 0);
        }
    }

    const bool f32m = (EPI == EPI_OUT) ? (*flag != 0u) : false;
    const int m_base = m_blk * BM + wm;
    const int n_base = n_blk * 128 + wn;
    const float scale = 0.044194173824159216f;  // 512^-0.5

    float inv[4][4];
    if (EPI == EPI_PV) {
        #pragma unroll
        for (int mi = 0; mi < 4; ++mi)
            #pragma unroll
            for (int r = 0; r < 4; ++r)
                inv[mi][r] = 1.0f / rl[f * NTOK + m_base + mi * 16 + quad * 4 + r];
    }
    float rs[4][4];
    if (EPI == EPI_SCEXP) {
        #pragma unroll
        for (int mi = 0; mi < 4; ++mi)
            #pragma unroll
            for (int r = 0; r < 4; ++r) rs[mi][r] = 0.0f;
    }

    #pragma unroll
    for (int mi = 0; mi < 4; ++mi) {
        #pragma unroll
        for (int ni = 0; ni < 4; ++ni) {
            int n = n_base + ni * 16 + l15;
            float bn = (EPI == EPI_QK) ? bf2f(bias[n]) : 0.0f;
            #pragma unroll
            for (int r = 0; r < 4; ++r) {
                int m = m_base + mi * 16 + quad * 4 + r;
                float v = acc[mi][ni][r];
                size_t idx = (size_t)f * cFS + (size_t)m * ldc + n;
                if (EPI == EPI_QK) {
                    ((u16*)C)[idx] = f2bf(v + bn);
                } else if (EPI == EPI_V) {
                    ((u16*)C)[idx] = f2bf(v + bf2f(bias[m]));
                } else if (EPI == EPI_SCEXP) {
                    float ex = __expf(v * scale);
                    rs[mi][r] += ex;
                    ((u16*)C)[idx] = f2bf(ex);
                } else if (EPI == EPI_PV) {
                    ((u16*)C)[idx] = f2bf(v * inv[mi][r]);
                } else {  // EPI_OUT
                    float r2 = v + bf2f(bias[m]) + ldx(resid, idx, f32m);
                    if (f32m) ((float*)C)[idx] = r2;
                    else      ((u16*)C)[idx]   = f2bf(r2);
                }
            }
        }
    }

    if (EPI == EPI_SCEXP) {
        #pragma unroll
        for (int mi = 0; mi < 4; ++mi) {
            #pragma unroll
            for (int r = 0; r < 4; ++r) {
                float s = rs[mi][r];
                s += __shfl_xor(s, 1, 64);
                s += __shfl_xor(s, 2, 64);
                s += __shfl_xor(s, 4, 64);
                s += __shfl_xor(s, 8, 64);
                if (l15 == 0)
                    atomicAdd(&rl[f * NTOK + m_base + mi * 16 + quad * 4 + r], s);
            }
        }
    }
}

// ---------------------------------------------------------------- launcher
extern "C" void kernel_launch(void* const* d_in, const int* in_sizes, int n_in,
                              void* d_out, int out_size, void* d_ws, size_t ws_size,
                              hipStream_t stream) {
    const void* x   = d_in[0];
    const void* gam = d_in[1];
    const void* bet = d_in[2];

    // Workspace (100 MiB):
    //   [0,4K) coef  [4K,+8K) partials  [12352) flag
    //   [16K,+2Mi) bf16 weights (contig)  [~2.1Mi,+4K) bf16 biases (contig)
    //   [3Mi) rl (16384 f32)
    //   [4Mi) xnt 16Mi (reused as obuf)  [20Mi) qkt 32Mi (q cols 0..511, k cols 512..1023)
    //   [52Mi) vt 16Mi
    //   [68Mi) P bf16 16x1024x1024 = 32Mi
    char* ws = (char*)d_ws;
    float2* coef     = (float2*)(ws);
    float2* partials = (float2*)(ws + 4096);
    u32*    flag     = (u32*)(ws + 12352);
    u16* cw[4] = { (u16*)(ws + 16384),              (u16*)(ws + 16384 +  524288ull),
                   (u16*)(ws + 16384 + 1048576ull), (u16*)(ws + 16384 + 1572864ull) };
    u16* cb[4] = { (u16*)(ws + 2113536ull),        (u16*)(ws + 2113536ull + 1024),
                   (u16*)(ws + 2113536ull + 2048), (u16*)(ws + 2113536ull + 3072) };
    float* rl  = (float*)(ws + (3ull << 20));
    u16*  xnt  = (u16*)(ws + (4ull  << 20));
    u16*  qkt  = (u16*)(ws + (20ull << 20));
    u16*  vt   = (u16*)(ws + (52ull << 20));
    u16*  pbuf = (u16*)(ws + (68ull << 20));
    u16*  obuf = xnt;

    detect_dtype<<<1, 256, 0, stream>>>((const u32*)x, flag);
    // conv_all also zeroes rl (blocks 1025..1088)
    conv_all<<<1089, 256, 0, stream>>>(d_in[3], d_in[5], d_in[7], d_in[9],
                                       d_in[4], d_in[6], d_in[8], d_in[10],
                                       cw[0], cb[0], rl, flag);
    gn_partial<<<NGRP * GN_SPLIT, 256, 0, stream>>>(x, partials, flag);
    gn_coef<<<2, 256, 0, stream>>>(partials, gam, bet, coef, flag);
    gn_apply_t<<<dim3(NPOS / 64, CCH / 64), 256, 0, stream>>>(x, coef, xnt, flag);

    // q,k fused: cw[0],cw[1] contiguous -> one GEMM, C[pos][1024] (q|k).
    // BM=256: grid 64x8 = 512 blocks (2/CU), 512 threads.
    dim3 gqk(NPOS / 256, 1024 / 128, 1);   // (64, 8)
    mfma_gemm<EPI_QK, true, false, 256><<<gqk, 512, 0, stream>>>(
        xnt, cw[0], qkt, cb[0], nullptr, flag, nullptr, CCH, CCH, 1024, CCH, 0, 0, 0);
    // v: C[cout][pos], A=Wv, B=xnt (128^2: M=512 -> only 2 blocks at BM=256)
    dim3 gv(NPOS / 128, CCH / 128, 1);    // (128, 4)
    mfma_gemm<EPI_V, false, false, 128><<<gv, 256, 0, stream>>>(
        cw[2], xnt, vt, cb[2], nullptr, flag, nullptr, CCH, CCH, NPOS, CCH, 0, 0, 0);

    // scores + exp + rowsum: P[f][i][j] = exp(scale * q_i.k_j), rl[f*1024+i] = sum_j
    // BM=256: grid (8 n, 4 m, 16 f) = 512 blocks (2/CU), frame->XCD pinned
    dim3 gsc(NTOK / 128, NTOK / 256, NFRM);   // (8, 4, 16)
    mfma_gemm<EPI_SCEXP, false, true, 256><<<gsc, 512, 0, stream>>>(
        qkt, qkt + 512, pbuf, nullptr, nullptr, flag, rl, 1024, 1024, NTOK, CCH,
        (long)NTOK * 1024, (long)NTOK * 1024, (long)NTOK * NTOK);

    // PV: obuf[i][c] = (P_i . V_c) / rl[i]  (128^2: BM=256 would be 256 blocks = 1/CU)
    dim3 gpv(CCH / 128, NTOK / 128, NFRM);    // (4, 8, 16), frame->XCD pinned
    mfma_gemm<EPI_PV, false, true, 128><<<gpv, 256, 0, stream>>>(
        pbuf, vt, obuf, nullptr, nullptr, flag, rl, NTOK, NPOS, CCH, NTOK,
        (long)NTOK * NTOK, NTOK, (long)NTOK * CCH);

    // out: C[cout][pos] = Wo . O + bo + x, poly store
    dim3 go(NPOS / 128, CCH / 128, 1);    // (128, 4)
    mfma_gemm<EPI_OUT, false, false, 128><<<go, 256, 0, stream>>>(
        cw[3], obuf, d_out, cb[3], x, flag, nullptr, CCH, CCH, NPOS, CCH, 0, 0, 0);
}